// Round 19
// baseline (569.330 us; speedup 1.0000x reference)
//
#include <hip/hip_runtime.h>
#include <hip/hip_cooperative_groups.h>

namespace cg = cooperative_groups;

// Chamfer forward: dist0[i] = min_j ||pc0[i]-pc1[j]||^2 ; out = mean(dist0[dist0<=2])
// N = M = 65536 i.i.d. N(0,1)^3 points, fp32.
// ROUND 19: single cooperative mega-kernel. R18 showed all my kernels below the
// harness's 41us ws-poison fill; ~30us of the remaining time was inter-dispatch
// gaps (9 dispatches). One 512x256 cooperative launch with grid.sync() between
// phases: zero -> count -> scanA -> scanB(blk0) -> scanC -> scatter -> query
// (2 lanes/q, fine grid G=64) -> pending (wave/query, medium grid G3=32) -> out.
// Phase bodies are the R16-R18 verified logic.

constexpr int   NPTS  = 65536;
constexpr int   G     = 64;
constexpr int   NC    = G * G * G;    // 262144
constexpr float H     = 0.125f;
constexpr float ORG   = -4.0f;
constexpr float INVH  = 8.0f;
constexpr int   G3    = 32;
constexpr int   NC3   = G3 * G3 * G3; // 32768
constexpr float H3    = 0.25f;
constexpr float INVH3 = 4.0f;
constexpr int   BLOCK = 256;
constexpr int   GRIDX = 512;          // = 2*NPTS/BLOCK exactly

__device__ __forceinline__ int cellOf(float x) {
  int c = (int)floorf((x - ORG) * INVH);
  return min(max(c, 0), G - 1);
}
__device__ __forceinline__ int cellOf3(float x) {
  int c = (int)floorf((x - ORG) * INVH3);
  return min(max(c, 0), G3 - 1);
}

__global__ __launch_bounds__(BLOCK) void mega_kernel(
    const float* __restrict__ pc0, const float* __restrict__ pc1,
    unsigned* __restrict__ counts0, unsigned* __restrict__ counts1,
    unsigned* __restrict__ counts3, unsigned* __restrict__ partials,
    unsigned* __restrict__ cur0, unsigned* __restrict__ cur1,
    unsigned* __restrict__ cur3,
    float4* __restrict__ q, float4* __restrict__ s, float4* __restrict__ s3,
    unsigned* __restrict__ wl, float* __restrict__ wlBest,
    unsigned* __restrict__ pendCnt, float* __restrict__ bkt,
    float* __restrict__ out, uint4* __restrict__ zbase, unsigned zvecs) {
  cg::grid_group grid = cg::this_grid();
  const int tid  = threadIdx.x;
  const int bid  = blockIdx.x;
  const int gid  = bid * BLOCK + tid;     // 0 .. 131071
  const int lane = tid & 63, wid = tid >> 6;

  __shared__ unsigned su[16];
  __shared__ float    sf[8];
  __shared__ int      snP;

  // ---- P0: zero counts1|counts0|counts3|misc (contiguous slab) ----
  for (unsigned i = gid; i < zvecs; i += GRIDX * BLOCK)
    zbase[i] = make_uint4(0u, 0u, 0u, 0u);
  grid.sync();

  // ---- P1: count (1 point per thread) ----
  if (gid < NPTS) {
    const float x = pc1[3 * gid], y = pc1[3 * gid + 1], z = pc1[3 * gid + 2];
    atomicAdd(&counts1[(cellOf(z) * G + cellOf(y)) * G + cellOf(x)], 1u);
    atomicAdd(&counts3[(cellOf3(z) * G3 + cellOf3(y)) * G3 + cellOf3(x)], 1u);
  } else {
    const int i = gid - NPTS;
    const float x = pc0[3 * i], y = pc0[3 * i + 1], z = pc0[3 * i + 2];
    atomicAdd(&counts0[(cellOf(z) * G + cellOf(y)) * G + cellOf(x)], 1u);
  }
  grid.sync();

  // ---- P2: per-block partial sums ----
  // blocks 0..255: counts1 chunk bid (1024 cells, 4/thread) + counts3 chunk bid
  // (128 cells, tid<128); blocks 256..511: counts0 chunk bid-256.
  {
    const unsigned* cnt = (bid < 256) ? counts1 : counts0;
    const int cb = (bid & 255) * 1024 + tid * 4;
    unsigned sum = cnt[cb] + cnt[cb + 1] + cnt[cb + 2] + cnt[cb + 3];
    for (int o = 32; o; o >>= 1) sum += __shfl_down(sum, o, 64);
    if (lane == 0) su[wid] = sum;
    __syncthreads();
    if (tid == 0) partials[bid] = su[0] + su[1] + su[2] + su[3];
    __syncthreads();
    if (bid < 256) {
      unsigned v3 = (tid < 128) ? counts3[bid * 128 + tid] : 0u;
      for (int o = 32; o; o >>= 1) v3 += __shfl_down(v3, o, 64);
      if (lane == 0 && wid < 2) su[8 + wid] = v3;
      __syncthreads();
      if (tid == 0) partials[512 + bid] = su[8] + su[9];
    }
  }
  grid.sync();

  // ---- P3: block 0 exclusive-scans the three 256-entry partial arrays ----
  if (bid == 0) {
    for (int a = 0; a < 3; ++a) {
      const int off = a * 256;
      const unsigned v = partials[off + tid];
      unsigned inc = v;
      for (int o = 1; o < 64; o <<= 1) {
        const unsigned t = __shfl_up(inc, o, 64);
        if (lane >= o) inc += t;
      }
      if (lane == 63) su[wid] = inc;
      __syncthreads();
      const unsigned woff = (wid >= 1 ? su[0] : 0u) + (wid >= 2 ? su[1] : 0u) +
                            (wid >= 3 ? su[2] : 0u);
      partials[off + tid] = woff + inc - v;
      __syncthreads();
    }
  }
  grid.sync();

  // ---- P4: block scan + offset -> CSR starts ----
  {
    const unsigned* cnt = (bid < 256) ? counts1 : counts0;
    unsigned* cur       = (bid < 256) ? cur1 : cur0;
    const int cb = (bid & 255) * 1024 + tid * 4;
    const unsigned c0 = cnt[cb], c1 = cnt[cb + 1], c2 = cnt[cb + 2], c3 = cnt[cb + 3];
    const unsigned tsum = c0 + c1 + c2 + c3;
    unsigned inc = tsum;
    for (int o = 1; o < 64; o <<= 1) {
      const unsigned t = __shfl_up(inc, o, 64);
      if (lane >= o) inc += t;
    }
    if (lane == 63) su[wid] = inc;
    __syncthreads();
    const unsigned woff = (wid >= 1 ? su[0] : 0u) + (wid >= 2 ? su[1] : 0u) +
                          (wid >= 3 ? su[2] : 0u);
    unsigned off = partials[bid] + woff + inc - tsum;
    cur[cb] = off; cur[cb + 1] = off + c0;
    cur[cb + 2] = off + c0 + c1; cur[cb + 3] = off + c0 + c1 + c2;
    __syncthreads();
    if (bid < 256) {   // medium grid: 128 cells/block, waves 0-1
      unsigned v3 = (tid < 128) ? counts3[bid * 128 + tid] : 0u;
      unsigned inc3 = v3;
      for (int o = 1; o < 64; o <<= 1) {
        const unsigned t = __shfl_up(inc3, o, 64);
        if (lane >= o) inc3 += t;
      }
      if (lane == 63 && wid < 2) su[8 + wid] = inc3;
      __syncthreads();
      if (tid < 128) {
        const unsigned woff3 = (wid == 1) ? su[8] : 0u;
        cur3[bid * 128 + tid] = partials[512 + bid] + woff3 + inc3 - v3;
      }
    }
  }
  grid.sync();

  // ---- P5: scatter (1 point per thread) ----
  if (gid < NPTS) {
    const float x = pc1[3 * gid], y = pc1[3 * gid + 1], z = pc1[3 * gid + 2];
    const float4 pt = make_float4(x, y, z, 0.f);
    s[atomicAdd(&cur1[(cellOf(z) * G + cellOf(y)) * G + cellOf(x)], 1u)] = pt;
    s3[atomicAdd(&cur3[(cellOf3(z) * G3 + cellOf3(y)) * G3 + cellOf3(x)], 1u)] = pt;
  } else {
    const int i = gid - NPTS;
    const float x = pc0[3 * i], y = pc0[3 * i + 1], z = pc0[3 * i + 2];
    q[atomicAdd(&cur0[(cellOf(z) * G + cellOf(y)) * G + cellOf(x)], 1u)] =
        make_float4(x, y, z, 0.f);
  }
  grid.sync();

  // ---- P6: query, fine rings 0..1, 2 lanes per query ----
  {
    const int i = gid >> 1, sub = gid & 1;
    const float4 p = q[i];
    const int cx = cellOf(p.x), cy = cellOf(p.y), cz = cellOf(p.z);
    const int x0 = max(cx - 1, 0), x1 = min(cx + 1, G - 1);
    unsigned rs[9], re[9];
#pragma unroll
    for (int rr = 0; rr < 9; ++rr) {
      const int zz = cz + rr / 3 - 1, yy = cy + rr % 3 - 1;
      const bool ok = (zz >= 0) && (zz < G) && (yy >= 0) && (yy < G);
      const int rb = ok ? (zz * G + yy) * G : 0;
      rs[rr] = ok ? ((rb + x0) ? cur1[rb + x0 - 1] : 0u) : 0u;
      re[rr] = ok ? cur1[rb + x1] : 0u;
    }
    float best = 3.4e38f;
#pragma unroll
    for (int rr = 0; rr < 9; ++rr) {
#pragma unroll 4
      for (unsigned j = rs[rr] + sub; j < re[rr]; j += 2) {
        const float4 c = s[j];
        const float dx = p.x - c.x, dy = p.y - c.y, dz = p.z - c.z;
        best = fminf(best, fmaf(dx, dx, fmaf(dy, dy, dz * dz)));
      }
    }
    best = fminf(best, __shfl_xor(best, 1, 64));

    float v = 0.f, c = 0.f;
    if (sub == 0) {
      if (best > H * H) {
        const unsigned k = atomicAdd(pendCnt, 1u);
        wl[k] = (unsigned)i; wlBest[k] = best;
      } else if (best <= 2.0f) { v = best; c = 1.0f; }
    }
    for (int o = 32; o; o >>= 1) {
      v += __shfl_down(v, o, 64);
      c += __shfl_down(c, o, 64);
    }
    if (lane == 0) { sf[wid] = v; sf[4 + wid] = c; }
    __syncthreads();
    if (tid == 0) {
      const float bv = sf[0] + sf[1] + sf[2] + sf[3];
      const float bc = sf[4] + sf[5] + sf[6] + sf[7];
      if (bc != 0.f) {
        atomicAdd(&bkt[2 * (bid & 63) + 0], bv);
        atomicAdd(&bkt[2 * (bid & 63) + 1], bc);
      }
    }
  }
  grid.sync();

  // ---- P7: pending, wave per query on the medium grid ----
  {
    if (tid == 0) snP = (int)atomicAdd(pendCnt, 0u);
    __syncthreads();
    const int gw = bid * (BLOCK / 64) + wid;
    const int nW = GRIDX * (BLOCK / 64);
    float v = 0.f, c = 0.f;
    for (int it = gw; it < snP; it += nW) {
      const unsigned qi = wl[it];
      const float4 p = q[qi];
      const int cx = cellOf3(p.x), cy = cellOf3(p.y), cz = cellOf3(p.z);
      float best = wlBest[it];
      for (int r = 1; r <= 8; ++r) {
        const float cov = H3 * (float)(r - 1);
        if (best <= cov * cov) break;
        if (best > 2.0f && cov * cov >= 2.0f) break;
        const int S = (r == 1) ? 9 : 8 * r + 2 * (2 * r - 1) * (2 * r - 1);
        float b = best;
        for (int sI = lane; sI < S; sI += 64) {
          int dz, dy, xa, xb;
          if (r == 1) {
            dz = sI / 3 - 1; dy = sI % 3 - 1; xa = cx - 1; xb = cx + 1;
          } else if (sI < 8 * r) {
            if (sI < 2 * r + 1)      { dz = -r; dy = sI - r; }
            else if (sI < 4 * r + 2) { dz =  r; dy = sI - (2 * r + 1) - r; }
            else { const int t2 = sI - (4 * r + 2); dz = (t2 >> 1) - (r - 1);
                   dy = (t2 & 1) ? r : -r; }
            xa = cx - r; xb = cx + r;
          } else {
            const int t2 = sI - 8 * r, ci = t2 >> 1, w1 = 2 * r - 1;
            dz = ci / w1 - (r - 1); dy = ci % w1 - (r - 1);
            xa = xb = (t2 & 1) ? cx + r : cx - r;
          }
          const int zz = cz + dz, yy = cy + dy;
          if (zz < 0 || zz >= G3 || yy < 0 || yy >= G3) continue;
          const int a = max(xa, 0), e = min(xb, G3 - 1);
          if (a > e) continue;
          const int rb = (zz * G3 + yy) * G3;
          const unsigned js = (rb + a) ? cur3[rb + a - 1] : 0u;
          const unsigned je = cur3[rb + e];
          for (unsigned j = js; j < je; ++j) {
            const float4 cd = s3[j];
            const float dx = p.x - cd.x, dyv = p.y - cd.y, dzv = p.z - cd.z;
            b = fminf(b, fmaf(dx, dx, fmaf(dyv, dyv, dzv * dzv)));
          }
        }
        for (int o = 32; o; o >>= 1) b = fminf(b, __shfl_xor(b, o, 64));
        best = b;
      }
      if (lane == 0 && best <= 2.0f) { v += best; c += 1.0f; }
    }
    __syncthreads();   // sf reuse after P6
    if (lane == 0) { sf[wid] = v; sf[4 + wid] = c; }
    __syncthreads();
    if (tid == 0) {
      const float bv = sf[0] + sf[1] + sf[2] + sf[3];
      const float bc = sf[4] + sf[5] + sf[6] + sf[7];
      if (bc != 0.f) {
        atomicAdd(&bkt[2 * (bid & 63) + 0], bv);
        atomicAdd(&bkt[2 * (bid & 63) + 1], bc);
      }
    }
  }
  grid.sync();

  // ---- P8: finalize (block 0) ----
  if (bid == 0) {
    const float val = (tid < 128) ? atomicAdd(&bkt[tid], 0.0f) : 0.0f;
    float sv = (tid & 1) ? 0.f : val;
    float cv = (tid & 1) ? val : 0.f;
    for (int o = 32; o; o >>= 1) {
      sv += __shfl_down(sv, o, 64);
      cv += __shfl_down(cv, o, 64);
    }
    __syncthreads();   // sf reuse
    if (lane == 0) { sf[wid] = sv; sf[4 + wid] = cv; }
    __syncthreads();
    if (tid == 0)
      out[0] = (sf[0] + sf[1] + sf[2] + sf[3]) / (sf[4] + sf[5] + sf[6] + sf[7]);
  }
}

extern "C" void kernel_launch(void* const* d_in, const int* in_sizes, int n_in,
                              void* d_out, int out_size, void* d_ws, size_t ws_size,
                              hipStream_t stream) {
  const float* pc0 = (const float*)d_in[0];
  const float* pc1 = (const float*)d_in[1];
  float* out = (float*)d_out;

  // slab carve-up; counts1|counts0|counts3|misc contiguous -> zeroed in-kernel
  char* w = (char*)d_ws;
  auto nxt = [&](size_t bytes) {
    char* p = w; w += (bytes + 255) & ~(size_t)255; return p;
  };
  unsigned* counts1  = (unsigned*)nxt((size_t)NC * 4);   // 1 MB
  unsigned* counts0  = (unsigned*)nxt((size_t)NC * 4);   // 1 MB
  unsigned* counts3  = (unsigned*)nxt((size_t)NC3 * 4);  // 128 KB
  char*     misc     = nxt(1024);                        // bkt[128] | pendCnt
  float*    bkt      = (float*)misc;
  unsigned* pendCnt  = (unsigned*)(misc + 512);
  unsigned* partials = (unsigned*)nxt((size_t)768 * 4);  // 3 KB
  unsigned* cur1     = (unsigned*)nxt((size_t)NC * 4);
  unsigned* cur0     = (unsigned*)nxt((size_t)NC * 4);
  unsigned* cur3     = (unsigned*)nxt((size_t)NC3 * 4);
  float4*   s        = (float4*)nxt((size_t)NPTS * 16);
  float4*   s3       = (float4*)nxt((size_t)NPTS * 16);
  float4*   q        = (float4*)nxt((size_t)NPTS * 16);
  unsigned* wl       = (unsigned*)nxt((size_t)NPTS * 4);
  float*    wlBest   = (float*)nxt((size_t)NPTS * 4);

  uint4*   zbase = (uint4*)counts1;
  unsigned zvecs = (unsigned)(((size_t)2 * NC * 4 + (size_t)NC3 * 4 + 1024) / 16);

  void* args[] = {&pc0, &pc1, &counts0, &counts1, &counts3, &partials,
                  &cur0, &cur1, &cur3, &q, &s, &s3, &wl, &wlBest,
                  &pendCnt, &bkt, &out, &zbase, &zvecs};
  hipLaunchCooperativeKernel((void*)mega_kernel, dim3(GRIDX), dim3(BLOCK),
                             args, 0, stream);
}

// Round 20
// 150.818 us; speedup vs baseline: 3.7750x; 3.7750x over previous
//
#include <hip/hip_runtime.h>

// Chamfer forward: dist0[i] = min_j ||pc0[i]-pc1[j]||^2 ; out = mean(dist0[dist0<=2])
// N = M = 65536 i.i.d. N(0,1)^3 points, fp32.
// Fine grid G=64 (h=0.125), counting sort, two-phase query. REVERT to R17 (best
// measured: 152.7us). R19's cooperative mega-kernel regressed 3.7x: grid.sync()
// on 8 non-coherent XCD L2s costs ~50-60us per sync (device-scope writeback/inv);
// kernel boundaries give the same coherence inside a ~5us launch gap.
// Structure: memset | count | scanA(256 blk) | scanB(1 blk) | scanC | scatter |
// query (2 lanes/q, fine rings 0..1, worklist push) | pending (wave/query,
// medium ring geometry over fine CSR, 4 fine rows per medium row) + finalize.
// Totals R16/R17/R18 = 154/153/157us across different work splits -> fixed floor:
// ~41us harness ws-poison fill (81% HBM peak) + ~8 launch gaps + ~85us kernels.

constexpr int   NPTS  = 65536;
constexpr int   G     = 64;
constexpr int   NC    = G * G * G;    // 262144 fine cells
constexpr float H     = 0.125f;
constexpr float ORG   = -4.0f;
constexpr float INVH  = 8.0f;
constexpr int   G3    = 32;           // medium geometry (phase 2 rings)
constexpr float H3    = 0.25f;
constexpr float INVH3 = 4.0f;
constexpr int   BLOCK = 256;
constexpr int   PBLOCKS = 256;        // pending kernel grid (done-counter)
constexpr int   SB    = 128;          // scan blocks per fine array
constexpr int   CHUNK = NC / SB;      // 2048 counts per scan block (2/thread)

__device__ __forceinline__ int cellOf(float x) {
  int c = (int)floorf((x - ORG) * INVH);
  return min(max(c, 0), G - 1);
}
__device__ __forceinline__ int cellOf3(float x) {
  int c = (int)floorf((x - ORG) * INVH3);
  return min(max(c, 0), G3 - 1);
}

__global__ __launch_bounds__(BLOCK) void count_kernel(
    const float* __restrict__ pc0, const float* __restrict__ pc1,
    unsigned* __restrict__ counts0, unsigned* __restrict__ counts1) {
  const int gid = blockIdx.x * BLOCK + threadIdx.x;
  const float* p; unsigned* cnt; int i;
  if (gid < NPTS) { p = pc1; cnt = counts1; i = gid; }
  else            { p = pc0; cnt = counts0; i = gid - NPTS; }
  const float x = p[3 * i], y = p[3 * i + 1], z = p[3 * i + 2];
  atomicAdd(&cnt[(cellOf(z) * G + cellOf(y)) * G + cellOf(x)], 1u);
}

// Phase A: per-block partial sums. grid=(SB,2); y=0->counts1, y=1->counts0.
__global__ __launch_bounds__(1024) void scan_partial_kernel(
    const unsigned* __restrict__ counts0, const unsigned* __restrict__ counts1,
    unsigned* __restrict__ partials) {
  const unsigned* counts = blockIdx.y ? counts0 : counts1;
  const int base = blockIdx.x * CHUNK + threadIdx.x * 2;
  unsigned sum = counts[base] + counts[base + 1];
  for (int o = 32; o; o >>= 1) sum += __shfl_down(sum, o, 64);
  __shared__ unsigned ws[16];
  if ((threadIdx.x & 63) == 0) ws[threadIdx.x >> 6] = sum;
  __syncthreads();
  if (threadIdx.x == 0) {
    unsigned t = 0;
    for (int w = 0; w < 16; ++w) t += ws[w];
    partials[blockIdx.y * SB + blockIdx.x] = t;
  }
}

// Phase B: one 256-thread block exclusively scans both 128-entry partial arrays.
__global__ __launch_bounds__(256) void scan_mid_kernel(
    unsigned* __restrict__ partials) {
  const int tid = threadIdx.x;
  const int g   = tid >> 7;
  const int li  = tid & 127;
  const unsigned v = partials[g * SB + li];
  unsigned inc = v;
  for (int o = 1; o < 64; o <<= 1) {
    const unsigned t = __shfl_up(inc, o, 64);
    if ((tid & 63) >= o) inc += t;
  }
  __shared__ unsigned wt[4];
  if ((tid & 63) == 63) wt[tid >> 6] = inc;
  __syncthreads();
  const unsigned woff = ((tid >> 6) & 1) ? wt[g << 1] : 0u;
  partials[g * SB + li] = woff + inc - v;
}

// Phase C: block scan + offset -> cur (CSR starts). grid=(SB,2).
__global__ __launch_bounds__(1024) void scan_final_kernel(
    const unsigned* __restrict__ counts0, unsigned* __restrict__ cur0,
    const unsigned* __restrict__ counts1, unsigned* __restrict__ cur1,
    const unsigned* __restrict__ partials) {
  const unsigned* counts = blockIdx.y ? counts0 : counts1;
  unsigned* cur          = blockIdx.y ? cur0    : cur1;
  const int tid = threadIdx.x;
  const int base = blockIdx.x * CHUNK + tid * 2;
  const unsigned a = counts[base], b = counts[base + 1];
  const unsigned tsum = a + b;
  unsigned inc = tsum;
  for (int o = 1; o < 64; o <<= 1) {
    const unsigned t = __shfl_up(inc, o, 64);
    if ((tid & 63) >= o) inc += t;
  }
  __shared__ unsigned wt[16];
  if ((tid & 63) == 63) wt[tid >> 6] = inc;
  __syncthreads();
  if (tid < 16) {
    unsigned w = wt[tid];
    for (int o = 1; o < 16; o <<= 1) {
      const unsigned t = __shfl_up(w, o, 16);
      if (tid >= o) w += t;
    }
    wt[tid] = w;
  }
  __syncthreads();
  const unsigned woff = (tid >> 6) ? wt[(tid >> 6) - 1] : 0u;
  const unsigned off =
      partials[blockIdx.y * SB + blockIdx.x] + woff + inc - tsum;
  cur[base] = off;
  cur[base + 1] = off + a;
}

// After scatter, cur[c] = CSR inclusive end of cell c (start = cur[c-1]).
__global__ __launch_bounds__(BLOCK) void scatter_kernel(
    const float* __restrict__ pc0, const float* __restrict__ pc1,
    unsigned* __restrict__ cur0, unsigned* __restrict__ cur1,
    float4* __restrict__ q, float4* __restrict__ s) {
  const int gid = blockIdx.x * BLOCK + threadIdx.x;
  const float* p; unsigned* cur; float4* dst; int i;
  if (gid < NPTS) { p = pc1; cur = cur1; dst = s; i = gid; }
  else            { p = pc0; cur = cur0; dst = q; i = gid - NPTS; }
  const float x = p[3 * i], y = p[3 * i + 1], z = p[3 * i + 2];
  const int cid = (cellOf(z) * G + cellOf(y)) * G + cellOf(x);
  dst[atomicAdd(&cur[cid], 1u)] = make_float4(x, y, z, 0.f);
}

// Phase 1: fine rings 0..1, 2 lanes per query; push unfinished to worklist.
__global__ __launch_bounds__(BLOCK) void query_kernel(
    const float4* __restrict__ q, const unsigned* __restrict__ ends,
    const float4* __restrict__ s,
    unsigned* __restrict__ wl, float* __restrict__ wlBest,
    unsigned* __restrict__ pendCnt, float* __restrict__ bkt) {
  const int gtid = blockIdx.x * BLOCK + threadIdx.x;
  const int i   = gtid >> 1;        // query index
  const int sub = gtid & 1;         // sub-lane
  const float4 p = q[i];
  const int cx = cellOf(p.x), cy = cellOf(p.y), cz = cellOf(p.z);
  const int x0 = max(cx - 1, 0), x1 = min(cx + 1, G - 1);

  unsigned rs[9], re[9];
#pragma unroll
  for (int rr = 0; rr < 9; ++rr) {
    const int zz = cz + rr / 3 - 1, yy = cy + rr % 3 - 1;
    const bool ok = (zz >= 0) && (zz < G) && (yy >= 0) && (yy < G);
    const int rb = ok ? (zz * G + yy) * G : 0;
    rs[rr] = ok ? ((rb + x0) ? ends[rb + x0 - 1] : 0u) : 0u;
    re[rr] = ok ? ends[rb + x1] : 0u;
  }
  float best = 3.4e38f;
#pragma unroll
  for (int rr = 0; rr < 9; ++rr) {
#pragma unroll 4
    for (unsigned j = rs[rr] + sub; j < re[rr]; j += 2) {
      const float4 c = s[j];
      const float dx = p.x - c.x, dy = p.y - c.y, dz = p.z - c.z;
      best = fminf(best, fmaf(dx, dx, fmaf(dy, dy, dz * dz)));
    }
  }
  best = fminf(best, __shfl_xor(best, 1, 64));   // combine the 2 sub-lanes

  float v = 0.f, c = 0.f;
  if (sub == 0) {
    if (best > H * H) {            // not provably exact -> phase 2
      const unsigned k = atomicAdd(pendCnt, 1u);
      wl[k] = (unsigned)i; wlBest[k] = best;
    } else if (best <= 2.0f) { v = best; c = 1.0f; }
  }

  for (int o = 32; o; o >>= 1) {
    v += __shfl_down(v, o, 64);
    c += __shfl_down(c, o, 64);
  }
  __shared__ float wsum[BLOCK / 64], wcnt[BLOCK / 64];
  const int wid = threadIdx.x >> 6;
  if ((threadIdx.x & 63) == 0) { wsum[wid] = v; wcnt[wid] = c; }
  __syncthreads();
  if (threadIdx.x == 0) {
    float bv = 0.f, bc = 0.f;
    for (int w = 0; w < BLOCK / 64; ++w) { bv += wsum[w]; bc += wcnt[w]; }
    if (bc != 0.f) {
      atomicAdd(&bkt[2 * (blockIdx.x & 63) + 0], bv);
      atomicAdd(&bkt[2 * (blockIdx.x & 63) + 1], bc);
    }
  }
}

// Phase 2: one wave per pending query; MEDIUM ring geometry over the FINE CSR
// (one medium row = 4 fine rows: zz in {2Z,2Z+1}, yy in {2Y,2Y+1}, x in
// [2Xa, 2Xb+1]). Ring 1 = full 3x3x3 medium; r=8 head always terminates.
__global__ __launch_bounds__(BLOCK) void pending_kernel(
    const float4* __restrict__ q,
    const unsigned* __restrict__ ends, const float4* __restrict__ s,
    const unsigned* __restrict__ wl, const float* __restrict__ wlBest,
    unsigned* __restrict__ pendCnt, float* __restrict__ bkt,
    unsigned* __restrict__ done, float* __restrict__ out) {
  __shared__ int snP;
  __shared__ float wsum[BLOCK / 64], wcnt[BLOCK / 64];
  __shared__ int isLast;
  __shared__ float fs[BLOCK / 64], fc[BLOCK / 64];
  if (threadIdx.x == 0) snP = (int)atomicAdd(pendCnt, 0u);
  __syncthreads();
  const int lane = threadIdx.x & 63, wid = threadIdx.x >> 6;
  const int gw = blockIdx.x * (BLOCK / 64) + wid;
  const int nW = PBLOCKS * (BLOCK / 64);
  float v = 0.f, c = 0.f;

  for (int it = gw; it < snP; it += nW) {
    const unsigned qi = wl[it];
    const float4 p = q[qi];
    const int cx = cellOf3(p.x), cy = cellOf3(p.y), cz = cellOf3(p.z);
    float best = wlBest[it];   // wave-uniform (same address)

    for (int r = 1; r <= 8; ++r) {
      const float cov = H3 * (float)(r - 1);    // unscanned dist lower bound
      if (best <= cov * cov) break;             // exact
      if (best > 2.0f && cov * cov >= 2.0f) break;  // masked out either way
      const int S = (r == 1) ? 9 : 8 * r + 2 * (2 * r - 1) * (2 * r - 1);
      float b = best;
      for (int sI = lane; sI < S; sI += 64) {
        int dz, dy, xa, xb;
        if (r == 1) {                           // full 3x3x3 medium rows
          dz = sI / 3 - 1; dy = sI % 3 - 1; xa = cx - 1; xb = cx + 1;
        } else if (sI < 8 * r) {                // shell faces: full x rows
          if (sI < 2 * r + 1)      { dz = -r; dy = sI - r; }
          else if (sI < 4 * r + 2) { dz =  r; dy = sI - (2 * r + 1) - r; }
          else { const int t2 = sI - (4 * r + 2); dz = (t2 >> 1) - (r - 1);
                 dy = (t2 & 1) ? r : -r; }
          xa = cx - r; xb = cx + r;
        } else {                                // interior rows: x = +/- r ends
          const int t2 = sI - 8 * r, ci = t2 >> 1, w1 = 2 * r - 1;
          dz = ci / w1 - (r - 1); dy = ci % w1 - (r - 1);
          xa = xb = (t2 & 1) ? cx + r : cx - r;
        }
        const int Z = cz + dz, Y = cy + dy;
        if (Z < 0 || Z >= G3 || Y < 0 || Y >= G3) continue;
        const int a3 = max(xa, 0), e3 = min(xb, G3 - 1);
        if (a3 > e3) continue;
        const int xs = 2 * a3, xe = 2 * e3 + 1; // fine x-span
        // 4 fine rows per medium row; ranges preloaded (independent loads)
        unsigned js[4], je[4];
#pragma unroll
        for (int k = 0; k < 4; ++k) {
          const int zz = 2 * Z + (k >> 1), yy = 2 * Y + (k & 1);
          const int rb = (zz * G + yy) * G;
          js[k] = (rb + xs) ? ends[rb + xs - 1] : 0u;
          je[k] = ends[rb + xe];
        }
#pragma unroll
        for (int k = 0; k < 4; ++k) {
          for (unsigned j = js[k]; j < je[k]; ++j) {
            const float4 cd = s[j];
            const float dx = p.x - cd.x, dyv = p.y - cd.y, dzv = p.z - cd.z;
            b = fminf(b, fmaf(dx, dx, fmaf(dyv, dyv, dzv * dzv)));
          }
        }
      }
      for (int o = 32; o; o >>= 1) b = fminf(b, __shfl_xor(b, o, 64));
      best = b;                                 // wave-uniform again
    }
    if (lane == 0 && best <= 2.0f) { v += best; c += 1.0f; }
  }

  if (lane == 0) { wsum[wid] = v; wcnt[wid] = c; }
  __syncthreads();
  if (threadIdx.x == 0) {
    float bv = 0.f, bc = 0.f;
    for (int w = 0; w < BLOCK / 64; ++w) { bv += wsum[w]; bc += wcnt[w]; }
    if (bc != 0.f) {
      atomicAdd(&bkt[2 * (blockIdx.x & 63) + 0], bv);
      atomicAdd(&bkt[2 * (blockIdx.x & 63) + 1], bc);
    }
    __threadfence();
    isLast = (atomicAdd(done, 1u) == (unsigned)(PBLOCKS - 1));
  }
  __syncthreads();
  if (isLast) {   // parallel coherent read of the 128 bucket slots + reduce
    const float val = (threadIdx.x < 128) ? atomicAdd(&bkt[threadIdx.x], 0.0f) : 0.0f;
    float sv = (threadIdx.x & 1) ? 0.f : val;
    float cv = (threadIdx.x & 1) ? val : 0.f;
    for (int o = 32; o; o >>= 1) {
      sv += __shfl_down(sv, o, 64);
      cv += __shfl_down(cv, o, 64);
    }
    if (lane == 0) { fs[wid] = sv; fc[wid] = cv; }
    __syncthreads();
    if (threadIdx.x == 0) {
      float S = 0.f, C = 0.f;
      for (int w = 0; w < BLOCK / 64; ++w) { S += fs[w]; C += fc[w]; }
      out[0] = S / C;
    }
  }
}

extern "C" void kernel_launch(void* const* d_in, const int* in_sizes, int n_in,
                              void* d_out, int out_size, void* d_ws, size_t ws_size,
                              hipStream_t stream) {
  const float* pc0 = (const float*)d_in[0];
  const float* pc1 = (const float*)d_in[1];
  float* out = (float*)d_out;

  // slab carve-up; counts1|counts0|misc contiguous -> single memset
  char* w = (char*)d_ws;
  auto nxt = [&](size_t bytes) {
    char* p = w; w += (bytes + 255) & ~(size_t)255; return p;
  };
  unsigned* counts1  = (unsigned*)nxt((size_t)NC * 4);           // 1 MB
  unsigned* counts0  = (unsigned*)nxt((size_t)NC * 4);           // 1 MB
  char*     misc     = nxt(1024);   // bkt[128] | done | pendCnt
  float*    bkt      = (float*)misc;
  unsigned* done     = (unsigned*)(misc + 512);
  unsigned* pendCnt  = (unsigned*)(misc + 516);
  unsigned* partials = (unsigned*)nxt((size_t)2 * SB * 4);       // 1 KB
  unsigned* cur1     = (unsigned*)nxt((size_t)NC * 4);           // 1 MB
  unsigned* cur0     = (unsigned*)nxt((size_t)NC * 4);           // 1 MB
  float4*   s        = (float4*)nxt((size_t)NPTS * 16);          // 1 MB
  float4*   q        = (float4*)nxt((size_t)NPTS * 16);          // 1 MB
  unsigned* wl       = (unsigned*)nxt((size_t)NPTS * 4);         // 256 KB
  float*    wlBest   = (float*)nxt((size_t)NPTS * 4);            // 256 KB

  hipMemsetAsync(counts1, 0, (size_t)2 * NC * 4 + 1024, stream);

  count_kernel<<<2 * NPTS / BLOCK, BLOCK, 0, stream>>>(pc0, pc1, counts0, counts1);
  scan_partial_kernel<<<dim3(SB, 2), 1024, 0, stream>>>(counts0, counts1, partials);
  scan_mid_kernel<<<1, 256, 0, stream>>>(partials);
  scan_final_kernel<<<dim3(SB, 2), 1024, 0, stream>>>(counts0, cur0,
                                                      counts1, cur1, partials);
  scatter_kernel<<<2 * NPTS / BLOCK, BLOCK, 0, stream>>>(
      pc0, pc1, cur0, cur1, q, s);
  query_kernel<<<2 * NPTS / BLOCK, BLOCK, 0, stream>>>(q, cur1, s, wl, wlBest,
                                                       pendCnt, bkt);
  pending_kernel<<<PBLOCKS, BLOCK, 0, stream>>>(q, cur1, s, wl, wlBest,
                                                pendCnt, bkt, done, out);
}

// Round 21
// 149.723 us; speedup vs baseline: 3.8025x; 1.0073x over previous
//
#include <hip/hip_runtime.h>

// Chamfer forward: dist0[i] = min_j ||pc0[i]-pc1[j]||^2 ; out = mean(dist0[dist0<=2])
// N = M = 65536 i.i.d. N(0,1)^3 points, fp32.
// Fine grid G=64 (h=0.125), counting sort, two-phase query. Structure = R20
// (best measured 150.8us) with ONE change: PBLOCKS 256 -> 1024.
// R20's pending (47us, VALUBusy 6%) was tail-imbalanced: ~3.3k pending queries
// over 1024 waves = ~3.2 stacked/wave; a deep query costs ~10-15us serial, so
// the kernel ran at worst-STACK time. 4096 waves -> <=1 query/wave -> worst-QUERY time.

constexpr int   NPTS  = 65536;
constexpr int   G     = 64;
constexpr int   NC    = G * G * G;    // 262144 fine cells
constexpr float H     = 0.125f;
constexpr float ORG   = -4.0f;
constexpr float INVH  = 8.0f;
constexpr int   G3    = 32;           // medium geometry (phase 2 rings)
constexpr float H3    = 0.25f;
constexpr float INVH3 = 4.0f;
constexpr int   BLOCK = 256;
constexpr int   PBLOCKS = 1024;       // pending grid: 4096 waves >= pending count
constexpr int   SB    = 128;          // scan blocks per fine array
constexpr int   CHUNK = NC / SB;      // 2048 counts per scan block (2/thread)

__device__ __forceinline__ int cellOf(float x) {
  int c = (int)floorf((x - ORG) * INVH);
  return min(max(c, 0), G - 1);
}
__device__ __forceinline__ int cellOf3(float x) {
  int c = (int)floorf((x - ORG) * INVH3);
  return min(max(c, 0), G3 - 1);
}

__global__ __launch_bounds__(BLOCK) void count_kernel(
    const float* __restrict__ pc0, const float* __restrict__ pc1,
    unsigned* __restrict__ counts0, unsigned* __restrict__ counts1) {
  const int gid = blockIdx.x * BLOCK + threadIdx.x;
  const float* p; unsigned* cnt; int i;
  if (gid < NPTS) { p = pc1; cnt = counts1; i = gid; }
  else            { p = pc0; cnt = counts0; i = gid - NPTS; }
  const float x = p[3 * i], y = p[3 * i + 1], z = p[3 * i + 2];
  atomicAdd(&cnt[(cellOf(z) * G + cellOf(y)) * G + cellOf(x)], 1u);
}

// Phase A: per-block partial sums. grid=(SB,2); y=0->counts1, y=1->counts0.
__global__ __launch_bounds__(1024) void scan_partial_kernel(
    const unsigned* __restrict__ counts0, const unsigned* __restrict__ counts1,
    unsigned* __restrict__ partials) {
  const unsigned* counts = blockIdx.y ? counts0 : counts1;
  const int base = blockIdx.x * CHUNK + threadIdx.x * 2;
  unsigned sum = counts[base] + counts[base + 1];
  for (int o = 32; o; o >>= 1) sum += __shfl_down(sum, o, 64);
  __shared__ unsigned ws[16];
  if ((threadIdx.x & 63) == 0) ws[threadIdx.x >> 6] = sum;
  __syncthreads();
  if (threadIdx.x == 0) {
    unsigned t = 0;
    for (int w = 0; w < 16; ++w) t += ws[w];
    partials[blockIdx.y * SB + blockIdx.x] = t;
  }
}

// Phase B: one 256-thread block exclusively scans both 128-entry partial arrays.
__global__ __launch_bounds__(256) void scan_mid_kernel(
    unsigned* __restrict__ partials) {
  const int tid = threadIdx.x;
  const int g   = tid >> 7;
  const int li  = tid & 127;
  const unsigned v = partials[g * SB + li];
  unsigned inc = v;
  for (int o = 1; o < 64; o <<= 1) {
    const unsigned t = __shfl_up(inc, o, 64);
    if ((tid & 63) >= o) inc += t;
  }
  __shared__ unsigned wt[4];
  if ((tid & 63) == 63) wt[tid >> 6] = inc;
  __syncthreads();
  const unsigned woff = ((tid >> 6) & 1) ? wt[g << 1] : 0u;
  partials[g * SB + li] = woff + inc - v;
}

// Phase C: block scan + offset -> cur (CSR starts). grid=(SB,2).
__global__ __launch_bounds__(1024) void scan_final_kernel(
    const unsigned* __restrict__ counts0, unsigned* __restrict__ cur0,
    const unsigned* __restrict__ counts1, unsigned* __restrict__ cur1,
    const unsigned* __restrict__ partials) {
  const unsigned* counts = blockIdx.y ? counts0 : counts1;
  unsigned* cur          = blockIdx.y ? cur0    : cur1;
  const int tid = threadIdx.x;
  const int base = blockIdx.x * CHUNK + tid * 2;
  const unsigned a = counts[base], b = counts[base + 1];
  const unsigned tsum = a + b;
  unsigned inc = tsum;
  for (int o = 1; o < 64; o <<= 1) {
    const unsigned t = __shfl_up(inc, o, 64);
    if ((tid & 63) >= o) inc += t;
  }
  __shared__ unsigned wt[16];
  if ((tid & 63) == 63) wt[tid >> 6] = inc;
  __syncthreads();
  if (tid < 16) {
    unsigned w = wt[tid];
    for (int o = 1; o < 16; o <<= 1) {
      const unsigned t = __shfl_up(w, o, 16);
      if (tid >= o) w += t;
    }
    wt[tid] = w;
  }
  __syncthreads();
  const unsigned woff = (tid >> 6) ? wt[(tid >> 6) - 1] : 0u;
  const unsigned off =
      partials[blockIdx.y * SB + blockIdx.x] + woff + inc - tsum;
  cur[base] = off;
  cur[base + 1] = off + a;
}

// After scatter, cur[c] = CSR inclusive end of cell c (start = cur[c-1]).
__global__ __launch_bounds__(BLOCK) void scatter_kernel(
    const float* __restrict__ pc0, const float* __restrict__ pc1,
    unsigned* __restrict__ cur0, unsigned* __restrict__ cur1,
    float4* __restrict__ q, float4* __restrict__ s) {
  const int gid = blockIdx.x * BLOCK + threadIdx.x;
  const float* p; unsigned* cur; float4* dst; int i;
  if (gid < NPTS) { p = pc1; cur = cur1; dst = s; i = gid; }
  else            { p = pc0; cur = cur0; dst = q; i = gid - NPTS; }
  const float x = p[3 * i], y = p[3 * i + 1], z = p[3 * i + 2];
  const int cid = (cellOf(z) * G + cellOf(y)) * G + cellOf(x);
  dst[atomicAdd(&cur[cid], 1u)] = make_float4(x, y, z, 0.f);
}

// Phase 1: fine rings 0..1, 2 lanes per query; push unfinished to worklist.
__global__ __launch_bounds__(BLOCK) void query_kernel(
    const float4* __restrict__ q, const unsigned* __restrict__ ends,
    const float4* __restrict__ s,
    unsigned* __restrict__ wl, float* __restrict__ wlBest,
    unsigned* __restrict__ pendCnt, float* __restrict__ bkt) {
  const int gtid = blockIdx.x * BLOCK + threadIdx.x;
  const int i   = gtid >> 1;        // query index
  const int sub = gtid & 1;         // sub-lane
  const float4 p = q[i];
  const int cx = cellOf(p.x), cy = cellOf(p.y), cz = cellOf(p.z);
  const int x0 = max(cx - 1, 0), x1 = min(cx + 1, G - 1);

  unsigned rs[9], re[9];
#pragma unroll
  for (int rr = 0; rr < 9; ++rr) {
    const int zz = cz + rr / 3 - 1, yy = cy + rr % 3 - 1;
    const bool ok = (zz >= 0) && (zz < G) && (yy >= 0) && (yy < G);
    const int rb = ok ? (zz * G + yy) * G : 0;
    rs[rr] = ok ? ((rb + x0) ? ends[rb + x0 - 1] : 0u) : 0u;
    re[rr] = ok ? ends[rb + x1] : 0u;
  }
  float best = 3.4e38f;
#pragma unroll
  for (int rr = 0; rr < 9; ++rr) {
#pragma unroll 4
    for (unsigned j = rs[rr] + sub; j < re[rr]; j += 2) {
      const float4 c = s[j];
      const float dx = p.x - c.x, dy = p.y - c.y, dz = p.z - c.z;
      best = fminf(best, fmaf(dx, dx, fmaf(dy, dy, dz * dz)));
    }
  }
  best = fminf(best, __shfl_xor(best, 1, 64));   // combine the 2 sub-lanes

  float v = 0.f, c = 0.f;
  if (sub == 0) {
    if (best > H * H) {            // not provably exact -> phase 2
      const unsigned k = atomicAdd(pendCnt, 1u);
      wl[k] = (unsigned)i; wlBest[k] = best;
    } else if (best <= 2.0f) { v = best; c = 1.0f; }
  }

  for (int o = 32; o; o >>= 1) {
    v += __shfl_down(v, o, 64);
    c += __shfl_down(c, o, 64);
  }
  __shared__ float wsum[BLOCK / 64], wcnt[BLOCK / 64];
  const int wid = threadIdx.x >> 6;
  if ((threadIdx.x & 63) == 0) { wsum[wid] = v; wcnt[wid] = c; }
  __syncthreads();
  if (threadIdx.x == 0) {
    float bv = 0.f, bc = 0.f;
    for (int w = 0; w < BLOCK / 64; ++w) { bv += wsum[w]; bc += wcnt[w]; }
    if (bc != 0.f) {
      atomicAdd(&bkt[2 * (blockIdx.x & 63) + 0], bv);
      atomicAdd(&bkt[2 * (blockIdx.x & 63) + 1], bc);
    }
  }
}

// Phase 2: one wave per pending query; MEDIUM ring geometry over the FINE CSR
// (one medium row = 4 fine rows: zz in {2Z,2Z+1}, yy in {2Y,2Y+1}, x in
// [2Xa, 2Xb+1]). Ring 1 = full 3x3x3 medium; r=8 head always terminates.
__global__ __launch_bounds__(BLOCK) void pending_kernel(
    const float4* __restrict__ q,
    const unsigned* __restrict__ ends, const float4* __restrict__ s,
    const unsigned* __restrict__ wl, const float* __restrict__ wlBest,
    unsigned* __restrict__ pendCnt, float* __restrict__ bkt,
    unsigned* __restrict__ done, float* __restrict__ out) {
  __shared__ int snP;
  __shared__ float wsum[BLOCK / 64], wcnt[BLOCK / 64];
  __shared__ int isLast;
  __shared__ float fs[BLOCK / 64], fc[BLOCK / 64];
  if (threadIdx.x == 0) snP = (int)atomicAdd(pendCnt, 0u);
  __syncthreads();
  const int lane = threadIdx.x & 63, wid = threadIdx.x >> 6;
  const int gw = blockIdx.x * (BLOCK / 64) + wid;
  const int nW = PBLOCKS * (BLOCK / 64);
  float v = 0.f, c = 0.f;

  for (int it = gw; it < snP; it += nW) {
    const unsigned qi = wl[it];
    const float4 p = q[qi];
    const int cx = cellOf3(p.x), cy = cellOf3(p.y), cz = cellOf3(p.z);
    float best = wlBest[it];   // wave-uniform (same address)

    for (int r = 1; r <= 8; ++r) {
      const float cov = H3 * (float)(r - 1);    // unscanned dist lower bound
      if (best <= cov * cov) break;             // exact
      if (best > 2.0f && cov * cov >= 2.0f) break;  // masked out either way
      const int S = (r == 1) ? 9 : 8 * r + 2 * (2 * r - 1) * (2 * r - 1);
      float b = best;
      for (int sI = lane; sI < S; sI += 64) {
        int dz, dy, xa, xb;
        if (r == 1) {                           // full 3x3x3 medium rows
          dz = sI / 3 - 1; dy = sI % 3 - 1; xa = cx - 1; xb = cx + 1;
        } else if (sI < 8 * r) {                // shell faces: full x rows
          if (sI < 2 * r + 1)      { dz = -r; dy = sI - r; }
          else if (sI < 4 * r + 2) { dz =  r; dy = sI - (2 * r + 1) - r; }
          else { const int t2 = sI - (4 * r + 2); dz = (t2 >> 1) - (r - 1);
                 dy = (t2 & 1) ? r : -r; }
          xa = cx - r; xb = cx + r;
        } else {                                // interior rows: x = +/- r ends
          const int t2 = sI - 8 * r, ci = t2 >> 1, w1 = 2 * r - 1;
          dz = ci / w1 - (r - 1); dy = ci % w1 - (r - 1);
          xa = xb = (t2 & 1) ? cx + r : cx - r;
        }
        const int Z = cz + dz, Y = cy + dy;
        if (Z < 0 || Z >= G3 || Y < 0 || Y >= G3) continue;
        const int a3 = max(xa, 0), e3 = min(xb, G3 - 1);
        if (a3 > e3) continue;
        const int xs = 2 * a3, xe = 2 * e3 + 1; // fine x-span
        // 4 fine rows per medium row; ranges preloaded (independent loads)
        unsigned js[4], je[4];
#pragma unroll
        for (int k = 0; k < 4; ++k) {
          const int zz = 2 * Z + (k >> 1), yy = 2 * Y + (k & 1);
          const int rb = (zz * G + yy) * G;
          js[k] = (rb + xs) ? ends[rb + xs - 1] : 0u;
          je[k] = ends[rb + xe];
        }
#pragma unroll
        for (int k = 0; k < 4; ++k) {
          for (unsigned j = js[k]; j < je[k]; ++j) {
            const float4 cd = s[j];
            const float dx = p.x - cd.x, dyv = p.y - cd.y, dzv = p.z - cd.z;
            b = fminf(b, fmaf(dx, dx, fmaf(dyv, dyv, dzv * dzv)));
          }
        }
      }
      for (int o = 32; o; o >>= 1) b = fminf(b, __shfl_xor(b, o, 64));
      best = b;                                 // wave-uniform again
    }
    if (lane == 0 && best <= 2.0f) { v += best; c += 1.0f; }
  }

  if (lane == 0) { wsum[wid] = v; wcnt[wid] = c; }
  __syncthreads();
  if (threadIdx.x == 0) {
    float bv = 0.f, bc = 0.f;
    for (int w = 0; w < BLOCK / 64; ++w) { bv += wsum[w]; bc += wcnt[w]; }
    if (bc != 0.f) {
      atomicAdd(&bkt[2 * (blockIdx.x & 63) + 0], bv);
      atomicAdd(&bkt[2 * (blockIdx.x & 63) + 1], bc);
    }
    __threadfence();
    isLast = (atomicAdd(done, 1u) == (unsigned)(PBLOCKS - 1));
  }
  __syncthreads();
  if (isLast) {   // parallel coherent read of the 128 bucket slots + reduce
    const float val = (threadIdx.x < 128) ? atomicAdd(&bkt[threadIdx.x], 0.0f) : 0.0f;
    float sv = (threadIdx.x & 1) ? 0.f : val;
    float cv = (threadIdx.x & 1) ? val : 0.f;
    for (int o = 32; o; o >>= 1) {
      sv += __shfl_down(sv, o, 64);
      cv += __shfl_down(cv, o, 64);
    }
    if (lane == 0) { fs[wid] = sv; fc[wid] = cv; }
    __syncthreads();
    if (threadIdx.x == 0) {
      float S = 0.f, C = 0.f;
      for (int w = 0; w < BLOCK / 64; ++w) { S += fs[w]; C += fc[w]; }
      out[0] = S / C;
    }
  }
}

extern "C" void kernel_launch(void* const* d_in, const int* in_sizes, int n_in,
                              void* d_out, int out_size, void* d_ws, size_t ws_size,
                              hipStream_t stream) {
  const float* pc0 = (const float*)d_in[0];
  const float* pc1 = (const float*)d_in[1];
  float* out = (float*)d_out;

  // slab carve-up; counts1|counts0|misc contiguous -> single memset
  char* w = (char*)d_ws;
  auto nxt = [&](size_t bytes) {
    char* p = w; w += (bytes + 255) & ~(size_t)255; return p;
  };
  unsigned* counts1  = (unsigned*)nxt((size_t)NC * 4);           // 1 MB
  unsigned* counts0  = (unsigned*)nxt((size_t)NC * 4);           // 1 MB
  char*     misc     = nxt(1024);   // bkt[128] | done | pendCnt
  float*    bkt      = (float*)misc;
  unsigned* done     = (unsigned*)(misc + 512);
  unsigned* pendCnt  = (unsigned*)(misc + 516);
  unsigned* partials = (unsigned*)nxt((size_t)2 * SB * 4);       // 1 KB
  unsigned* cur1     = (unsigned*)nxt((size_t)NC * 4);           // 1 MB
  unsigned* cur0     = (unsigned*)nxt((size_t)NC * 4);           // 1 MB
  float4*   s        = (float4*)nxt((size_t)NPTS * 16);          // 1 MB
  float4*   q        = (float4*)nxt((size_t)NPTS * 16);          // 1 MB
  unsigned* wl       = (unsigned*)nxt((size_t)NPTS * 4);         // 256 KB
  float*    wlBest   = (float*)nxt((size_t)NPTS * 4);            // 256 KB

  hipMemsetAsync(counts1, 0, (size_t)2 * NC * 4 + 1024, stream);

  count_kernel<<<2 * NPTS / BLOCK, BLOCK, 0, stream>>>(pc0, pc1, counts0, counts1);
  scan_partial_kernel<<<dim3(SB, 2), 1024, 0, stream>>>(counts0, counts1, partials);
  scan_mid_kernel<<<1, 256, 0, stream>>>(partials);
  scan_final_kernel<<<dim3(SB, 2), 1024, 0, stream>>>(counts0, cur0,
                                                      counts1, cur1, partials);
  scatter_kernel<<<2 * NPTS / BLOCK, BLOCK, 0, stream>>>(
      pc0, pc1, cur0, cur1, q, s);
  query_kernel<<<2 * NPTS / BLOCK, BLOCK, 0, stream>>>(q, cur1, s, wl, wlBest,
                                                       pendCnt, bkt);
  pending_kernel<<<PBLOCKS, BLOCK, 0, stream>>>(q, cur1, s, wl, wlBest,
                                                pendCnt, bkt, done, out);
}

// Round 22
// 148.223 us; speedup vs baseline: 3.8410x; 1.0101x over previous
//
#include <hip/hip_runtime.h>

// Chamfer forward: dist0[i] = min_j ||pc0[i]-pc1[j]||^2 ; out = mean(dist0[dist0<=2])
// N = M = 65536 i.i.d. N(0,1)^3 points, fp32.
// Fine grid G=64 (h=0.125), counting sort, two-phase query. Structure = R21
// (best measured 149.7us) with ONE change: #pragma unroll 4 on pending's inner
// candidate loop. R21 showed pending (43us, VALUBusy 7%) is bound by ONE worst
// query: an edge point whose r~7 shell sweeps the dense core -> a lane segment
// with ~300 candidates = ~300 serial dependent loads (~25us). Unroll-4 puts 4
// loads in flight -> ~4x shorter chain (query_kernel already does this).

constexpr int   NPTS  = 65536;
constexpr int   G     = 64;
constexpr int   NC    = G * G * G;    // 262144 fine cells
constexpr float H     = 0.125f;
constexpr float ORG   = -4.0f;
constexpr float INVH  = 8.0f;
constexpr int   G3    = 32;           // medium geometry (phase 2 rings)
constexpr float H3    = 0.25f;
constexpr float INVH3 = 4.0f;
constexpr int   BLOCK = 256;
constexpr int   PBLOCKS = 1024;       // pending grid: 4096 waves >= pending count
constexpr int   SB    = 128;          // scan blocks per fine array
constexpr int   CHUNK = NC / SB;      // 2048 counts per scan block (2/thread)

__device__ __forceinline__ int cellOf(float x) {
  int c = (int)floorf((x - ORG) * INVH);
  return min(max(c, 0), G - 1);
}
__device__ __forceinline__ int cellOf3(float x) {
  int c = (int)floorf((x - ORG) * INVH3);
  return min(max(c, 0), G3 - 1);
}

__global__ __launch_bounds__(BLOCK) void count_kernel(
    const float* __restrict__ pc0, const float* __restrict__ pc1,
    unsigned* __restrict__ counts0, unsigned* __restrict__ counts1) {
  const int gid = blockIdx.x * BLOCK + threadIdx.x;
  const float* p; unsigned* cnt; int i;
  if (gid < NPTS) { p = pc1; cnt = counts1; i = gid; }
  else            { p = pc0; cnt = counts0; i = gid - NPTS; }
  const float x = p[3 * i], y = p[3 * i + 1], z = p[3 * i + 2];
  atomicAdd(&cnt[(cellOf(z) * G + cellOf(y)) * G + cellOf(x)], 1u);
}

// Phase A: per-block partial sums. grid=(SB,2); y=0->counts1, y=1->counts0.
__global__ __launch_bounds__(1024) void scan_partial_kernel(
    const unsigned* __restrict__ counts0, const unsigned* __restrict__ counts1,
    unsigned* __restrict__ partials) {
  const unsigned* counts = blockIdx.y ? counts0 : counts1;
  const int base = blockIdx.x * CHUNK + threadIdx.x * 2;
  unsigned sum = counts[base] + counts[base + 1];
  for (int o = 32; o; o >>= 1) sum += __shfl_down(sum, o, 64);
  __shared__ unsigned ws[16];
  if ((threadIdx.x & 63) == 0) ws[threadIdx.x >> 6] = sum;
  __syncthreads();
  if (threadIdx.x == 0) {
    unsigned t = 0;
    for (int w = 0; w < 16; ++w) t += ws[w];
    partials[blockIdx.y * SB + blockIdx.x] = t;
  }
}

// Phase B: one 256-thread block exclusively scans both 128-entry partial arrays.
__global__ __launch_bounds__(256) void scan_mid_kernel(
    unsigned* __restrict__ partials) {
  const int tid = threadIdx.x;
  const int g   = tid >> 7;
  const int li  = tid & 127;
  const unsigned v = partials[g * SB + li];
  unsigned inc = v;
  for (int o = 1; o < 64; o <<= 1) {
    const unsigned t = __shfl_up(inc, o, 64);
    if ((tid & 63) >= o) inc += t;
  }
  __shared__ unsigned wt[4];
  if ((tid & 63) == 63) wt[tid >> 6] = inc;
  __syncthreads();
  const unsigned woff = ((tid >> 6) & 1) ? wt[g << 1] : 0u;
  partials[g * SB + li] = woff + inc - v;
}

// Phase C: block scan + offset -> cur (CSR starts). grid=(SB,2).
__global__ __launch_bounds__(1024) void scan_final_kernel(
    const unsigned* __restrict__ counts0, unsigned* __restrict__ cur0,
    const unsigned* __restrict__ counts1, unsigned* __restrict__ cur1,
    const unsigned* __restrict__ partials) {
  const unsigned* counts = blockIdx.y ? counts0 : counts1;
  unsigned* cur          = blockIdx.y ? cur0    : cur1;
  const int tid = threadIdx.x;
  const int base = blockIdx.x * CHUNK + tid * 2;
  const unsigned a = counts[base], b = counts[base + 1];
  const unsigned tsum = a + b;
  unsigned inc = tsum;
  for (int o = 1; o < 64; o <<= 1) {
    const unsigned t = __shfl_up(inc, o, 64);
    if ((tid & 63) >= o) inc += t;
  }
  __shared__ unsigned wt[16];
  if ((tid & 63) == 63) wt[tid >> 6] = inc;
  __syncthreads();
  if (tid < 16) {
    unsigned w = wt[tid];
    for (int o = 1; o < 16; o <<= 1) {
      const unsigned t = __shfl_up(w, o, 16);
      if (tid >= o) w += t;
    }
    wt[tid] = w;
  }
  __syncthreads();
  const unsigned woff = (tid >> 6) ? wt[(tid >> 6) - 1] : 0u;
  const unsigned off =
      partials[blockIdx.y * SB + blockIdx.x] + woff + inc - tsum;
  cur[base] = off;
  cur[base + 1] = off + a;
}

// After scatter, cur[c] = CSR inclusive end of cell c (start = cur[c-1]).
__global__ __launch_bounds__(BLOCK) void scatter_kernel(
    const float* __restrict__ pc0, const float* __restrict__ pc1,
    unsigned* __restrict__ cur0, unsigned* __restrict__ cur1,
    float4* __restrict__ q, float4* __restrict__ s) {
  const int gid = blockIdx.x * BLOCK + threadIdx.x;
  const float* p; unsigned* cur; float4* dst; int i;
  if (gid < NPTS) { p = pc1; cur = cur1; dst = s; i = gid; }
  else            { p = pc0; cur = cur0; dst = q; i = gid - NPTS; }
  const float x = p[3 * i], y = p[3 * i + 1], z = p[3 * i + 2];
  const int cid = (cellOf(z) * G + cellOf(y)) * G + cellOf(x);
  dst[atomicAdd(&cur[cid], 1u)] = make_float4(x, y, z, 0.f);
}

// Phase 1: fine rings 0..1, 2 lanes per query; push unfinished to worklist.
__global__ __launch_bounds__(BLOCK) void query_kernel(
    const float4* __restrict__ q, const unsigned* __restrict__ ends,
    const float4* __restrict__ s,
    unsigned* __restrict__ wl, float* __restrict__ wlBest,
    unsigned* __restrict__ pendCnt, float* __restrict__ bkt) {
  const int gtid = blockIdx.x * BLOCK + threadIdx.x;
  const int i   = gtid >> 1;        // query index
  const int sub = gtid & 1;         // sub-lane
  const float4 p = q[i];
  const int cx = cellOf(p.x), cy = cellOf(p.y), cz = cellOf(p.z);
  const int x0 = max(cx - 1, 0), x1 = min(cx + 1, G - 1);

  unsigned rs[9], re[9];
#pragma unroll
  for (int rr = 0; rr < 9; ++rr) {
    const int zz = cz + rr / 3 - 1, yy = cy + rr % 3 - 1;
    const bool ok = (zz >= 0) && (zz < G) && (yy >= 0) && (yy < G);
    const int rb = ok ? (zz * G + yy) * G : 0;
    rs[rr] = ok ? ((rb + x0) ? ends[rb + x0 - 1] : 0u) : 0u;
    re[rr] = ok ? ends[rb + x1] : 0u;
  }
  float best = 3.4e38f;
#pragma unroll
  for (int rr = 0; rr < 9; ++rr) {
#pragma unroll 4
    for (unsigned j = rs[rr] + sub; j < re[rr]; j += 2) {
      const float4 c = s[j];
      const float dx = p.x - c.x, dy = p.y - c.y, dz = p.z - c.z;
      best = fminf(best, fmaf(dx, dx, fmaf(dy, dy, dz * dz)));
    }
  }
  best = fminf(best, __shfl_xor(best, 1, 64));   // combine the 2 sub-lanes

  float v = 0.f, c = 0.f;
  if (sub == 0) {
    if (best > H * H) {            // not provably exact -> phase 2
      const unsigned k = atomicAdd(pendCnt, 1u);
      wl[k] = (unsigned)i; wlBest[k] = best;
    } else if (best <= 2.0f) { v = best; c = 1.0f; }
  }

  for (int o = 32; o; o >>= 1) {
    v += __shfl_down(v, o, 64);
    c += __shfl_down(c, o, 64);
  }
  __shared__ float wsum[BLOCK / 64], wcnt[BLOCK / 64];
  const int wid = threadIdx.x >> 6;
  if ((threadIdx.x & 63) == 0) { wsum[wid] = v; wcnt[wid] = c; }
  __syncthreads();
  if (threadIdx.x == 0) {
    float bv = 0.f, bc = 0.f;
    for (int w = 0; w < BLOCK / 64; ++w) { bv += wsum[w]; bc += wcnt[w]; }
    if (bc != 0.f) {
      atomicAdd(&bkt[2 * (blockIdx.x & 63) + 0], bv);
      atomicAdd(&bkt[2 * (blockIdx.x & 63) + 1], bc);
    }
  }
}

// Phase 2: one wave per pending query; MEDIUM ring geometry over the FINE CSR
// (one medium row = 4 fine rows). Ring 1 = full 3x3x3 medium; r=8 head always
// terminates. Candidate loop unroll-4: 4 loads in flight per lane.
__global__ __launch_bounds__(BLOCK) void pending_kernel(
    const float4* __restrict__ q,
    const unsigned* __restrict__ ends, const float4* __restrict__ s,
    const unsigned* __restrict__ wl, const float* __restrict__ wlBest,
    unsigned* __restrict__ pendCnt, float* __restrict__ bkt,
    unsigned* __restrict__ done, float* __restrict__ out) {
  __shared__ int snP;
  __shared__ float wsum[BLOCK / 64], wcnt[BLOCK / 64];
  __shared__ int isLast;
  __shared__ float fs[BLOCK / 64], fc[BLOCK / 64];
  if (threadIdx.x == 0) snP = (int)atomicAdd(pendCnt, 0u);
  __syncthreads();
  const int lane = threadIdx.x & 63, wid = threadIdx.x >> 6;
  const int gw = blockIdx.x * (BLOCK / 64) + wid;
  const int nW = PBLOCKS * (BLOCK / 64);
  float v = 0.f, c = 0.f;

  for (int it = gw; it < snP; it += nW) {
    const unsigned qi = wl[it];
    const float4 p = q[qi];
    const int cx = cellOf3(p.x), cy = cellOf3(p.y), cz = cellOf3(p.z);
    float best = wlBest[it];   // wave-uniform (same address)

    for (int r = 1; r <= 8; ++r) {
      const float cov = H3 * (float)(r - 1);    // unscanned dist lower bound
      if (best <= cov * cov) break;             // exact
      if (best > 2.0f && cov * cov >= 2.0f) break;  // masked out either way
      const int S = (r == 1) ? 9 : 8 * r + 2 * (2 * r - 1) * (2 * r - 1);
      float b = best;
      for (int sI = lane; sI < S; sI += 64) {
        int dz, dy, xa, xb;
        if (r == 1) {                           // full 3x3x3 medium rows
          dz = sI / 3 - 1; dy = sI % 3 - 1; xa = cx - 1; xb = cx + 1;
        } else if (sI < 8 * r) {                // shell faces: full x rows
          if (sI < 2 * r + 1)      { dz = -r; dy = sI - r; }
          else if (sI < 4 * r + 2) { dz =  r; dy = sI - (2 * r + 1) - r; }
          else { const int t2 = sI - (4 * r + 2); dz = (t2 >> 1) - (r - 1);
                 dy = (t2 & 1) ? r : -r; }
          xa = cx - r; xb = cx + r;
        } else {                                // interior rows: x = +/- r ends
          const int t2 = sI - 8 * r, ci = t2 >> 1, w1 = 2 * r - 1;
          dz = ci / w1 - (r - 1); dy = ci % w1 - (r - 1);
          xa = xb = (t2 & 1) ? cx + r : cx - r;
        }
        const int Z = cz + dz, Y = cy + dy;
        if (Z < 0 || Z >= G3 || Y < 0 || Y >= G3) continue;
        const int a3 = max(xa, 0), e3 = min(xb, G3 - 1);
        if (a3 > e3) continue;
        const int xs = 2 * a3, xe = 2 * e3 + 1; // fine x-span
        // 4 fine rows per medium row; ranges preloaded (independent loads)
        unsigned js[4], je[4];
#pragma unroll
        for (int k = 0; k < 4; ++k) {
          const int zz = 2 * Z + (k >> 1), yy = 2 * Y + (k & 1);
          const int rb = (zz * G + yy) * G;
          js[k] = (rb + xs) ? ends[rb + xs - 1] : 0u;
          je[k] = ends[rb + xe];
        }
#pragma unroll
        for (int k = 0; k < 4; ++k) {
#pragma unroll 4
          for (unsigned j = js[k]; j < je[k]; ++j) {
            const float4 cd = s[j];
            const float dx = p.x - cd.x, dyv = p.y - cd.y, dzv = p.z - cd.z;
            b = fminf(b, fmaf(dx, dx, fmaf(dyv, dyv, dzv * dzv)));
          }
        }
      }
      for (int o = 32; o; o >>= 1) b = fminf(b, __shfl_xor(b, o, 64));
      best = b;                                 // wave-uniform again
    }
    if (lane == 0 && best <= 2.0f) { v += best; c += 1.0f; }
  }

  if (lane == 0) { wsum[wid] = v; wcnt[wid] = c; }
  __syncthreads();
  if (threadIdx.x == 0) {
    float bv = 0.f, bc = 0.f;
    for (int w = 0; w < BLOCK / 64; ++w) { bv += wsum[w]; bc += wcnt[w]; }
    if (bc != 0.f) {
      atomicAdd(&bkt[2 * (blockIdx.x & 63) + 0], bv);
      atomicAdd(&bkt[2 * (blockIdx.x & 63) + 1], bc);
    }
    __threadfence();
    isLast = (atomicAdd(done, 1u) == (unsigned)(PBLOCKS - 1));
  }
  __syncthreads();
  if (isLast) {   // parallel coherent read of the 128 bucket slots + reduce
    const float val = (threadIdx.x < 128) ? atomicAdd(&bkt[threadIdx.x], 0.0f) : 0.0f;
    float sv = (threadIdx.x & 1) ? 0.f : val;
    float cv = (threadIdx.x & 1) ? val : 0.f;
    for (int o = 32; o; o >>= 1) {
      sv += __shfl_down(sv, o, 64);
      cv += __shfl_down(cv, o, 64);
    }
    if (lane == 0) { fs[wid] = sv; fc[wid] = cv; }
    __syncthreads();
    if (threadIdx.x == 0) {
      float S = 0.f, C = 0.f;
      for (int w = 0; w < BLOCK / 64; ++w) { S += fs[w]; C += fc[w]; }
      out[0] = S / C;
    }
  }
}

extern "C" void kernel_launch(void* const* d_in, const int* in_sizes, int n_in,
                              void* d_out, int out_size, void* d_ws, size_t ws_size,
                              hipStream_t stream) {
  const float* pc0 = (const float*)d_in[0];
  const float* pc1 = (const float*)d_in[1];
  float* out = (float*)d_out;

  // slab carve-up; counts1|counts0|misc contiguous -> single memset
  char* w = (char*)d_ws;
  auto nxt = [&](size_t bytes) {
    char* p = w; w += (bytes + 255) & ~(size_t)255; return p;
  };
  unsigned* counts1  = (unsigned*)nxt((size_t)NC * 4);           // 1 MB
  unsigned* counts0  = (unsigned*)nxt((size_t)NC * 4);           // 1 MB
  char*     misc     = nxt(1024);   // bkt[128] | done | pendCnt
  float*    bkt      = (float*)misc;
  unsigned* done     = (unsigned*)(misc + 512);
  unsigned* pendCnt  = (unsigned*)(misc + 516);
  unsigned* partials = (unsigned*)nxt((size_t)2 * SB * 4);       // 1 KB
  unsigned* cur1     = (unsigned*)nxt((size_t)NC * 4);           // 1 MB
  unsigned* cur0     = (unsigned*)nxt((size_t)NC * 4);           // 1 MB
  float4*   s        = (float4*)nxt((size_t)NPTS * 16);          // 1 MB
  float4*   q        = (float4*)nxt((size_t)NPTS * 16);          // 1 MB
  unsigned* wl       = (unsigned*)nxt((size_t)NPTS * 4);         // 256 KB
  float*    wlBest   = (float*)nxt((size_t)NPTS * 4);            // 256 KB

  hipMemsetAsync(counts1, 0, (size_t)2 * NC * 4 + 1024, stream);

  count_kernel<<<2 * NPTS / BLOCK, BLOCK, 0, stream>>>(pc0, pc1, counts0, counts1);
  scan_partial_kernel<<<dim3(SB, 2), 1024, 0, stream>>>(counts0, counts1, partials);
  scan_mid_kernel<<<1, 256, 0, stream>>>(partials);
  scan_final_kernel<<<dim3(SB, 2), 1024, 0, stream>>>(counts0, cur0,
                                                      counts1, cur1, partials);
  scatter_kernel<<<2 * NPTS / BLOCK, BLOCK, 0, stream>>>(
      pc0, pc1, cur0, cur1, q, s);
  query_kernel<<<2 * NPTS / BLOCK, BLOCK, 0, stream>>>(q, cur1, s, wl, wlBest,
                                                       pendCnt, bkt);
  pending_kernel<<<PBLOCKS, BLOCK, 0, stream>>>(q, cur1, s, wl, wlBest,
                                                pendCnt, bkt, done, out);
}